// Round 9
// baseline (77.790 us; speedup 1.0000x reference)
//
#include <hip/hip_runtime.h>

#define DD 48
#define HH 256
#define WW 256
#define HM 128
#define WM 128
#define PLANE (DD*HH*WW)
#define MPLANE (DD*HM*WM)

// LDS halo: output tile 4z x 16y x 16x, halo +-2z, +-5y, +-5x (zero-padded)
#define SZ 9
#define SY 27
#define SXL 27
#define SLICE (SY*SXL)      // 729
#define SCELLS (SZ*SLICE)   // 6561 cells * 8B = 52488 B -> 3 blocks/CU

typedef __attribute__((ext_vector_type(2))) float f32x2;

// pinned mvf row-pair load: rows my0 and my0+1 (+512B)
#define MVF_PAIR(da, db, vo, bp) \
  asm volatile("global_load_dwordx2 %0, %2, %3\n\t" \
               "global_load_dwordx2 %1, %2, %3 offset:512" \
               : "=&v"(da), "=&v"(db) : "v"(vo), "s"(bp))

// pinned LDS read with immediate offset (S at LDS offset 0: lone extern shared)
#define DSR(d, a, offstr) \
  asm volatile("ds_read_b64 %0, %1 offset:" offstr : "=v"(d) : "v"(a))

__global__ __launch_bounds__(512, 4) void mvf_warp(
    const float* __restrict__ img,   // [48,256,256,2]
    const float* __restrict__ mvf,   // [4,3,48,128,128]
    float* __restrict__ out)         // [5,48,256,256,2]
{
    extern __shared__ f32x2 S[];     // SCELLS
    const f32x2* img2 = (const f32x2*)img;
    f32x2* out2 = (f32x2*)out;
    const int tid = threadIdx.x;

    // 3072 blocks; XCD k owns ty band {2k, 2k+1}; tz swept slow
    const int bid = blockIdx.x;
    const int xcd = bid & 7;
    const int lin = bid >> 3;          // 0..383
    const int tx  = lin & 15;
    const int rest = lin >> 4;         // 0..23
    const int ty  = xcd * 2 + (rest & 1);
    const int tz  = rest >> 1;         // 0..11

    const int z0t = tz * 4, y0t = ty * 16, x0t = tx * 16;
    const int oz = z0t - 2, oy = y0t - 5, ox = x0t - 5;

    const int x  = x0t + (tid & 15);
    const int y  = y0t + ((tid >> 4) & 15);
    const int zb = z0t + (tid >> 8);   // z = zb + 2k, k=0..1

    // ---- mvf bilinear setup (2x half-pixel upsample, clamped) ----
    float ys = fminf(fmaxf((float)y * 0.5f - 0.25f, 0.0f), 127.0f);
    float xs = fminf(fmaxf((float)x * 0.5f - 0.25f, 0.0f), 127.0f);
    int my0 = min((int)ys, HM - 2);
    int mx0 = min((int)xs, WM - 2);
    float wyk = ys - (float)my0, wxk = xs - (float)mx0;
    float w00 = (1.0f - wyk) * (1.0f - wxk);
    float w01 = (1.0f - wyk) * wxk;
    float w10 = wyk * (1.0f - wxk);
    float w11 = wyk * wxk;

    const unsigned voff0 = (unsigned)((zb * (HM*WM) + my0 * WM + mx0) * 4);

    // ring of 2 half-batches (2 phases x 3 ch each): 24 f32x2
    f32x2 Ra[2][6], Rb[2][6];

    // ---- prologue: issue hb0 (k=0, phases 0,1) ----
    MVF_PAIR(Ra[0][0], Rb[0][0], voff0, mvf + 0*MPLANE);
    MVF_PAIR(Ra[0][1], Rb[0][1], voff0, mvf + 1*MPLANE);
    MVF_PAIR(Ra[0][2], Rb[0][2], voff0, mvf + 2*MPLANE);
    MVF_PAIR(Ra[0][3], Rb[0][3], voff0, mvf + 3*MPLANE);
    MVF_PAIR(Ra[0][4], Rb[0][4], voff0, mvf + 4*MPLANE);
    MVF_PAIR(Ra[0][5], Rb[0][5], voff0, mvf + 5*MPLANE);
    __builtin_amdgcn_sched_barrier(0);

    // ---- stage ZERO-PADDED image halo into LDS ----
    {
        int c0 = tid;
        int iy0 = c0 / SXL, ix0 = c0 - iy0 * SXL;
        int gy0 = oy + iy0, gx0 = ox + ix0;
        bool vy0 = (gy0 >= 0) && (gy0 < HH) && (gx0 >= 0) && (gx0 < WW);
        int yx0 = min(max(gy0,0),HH-1) * WW + min(max(gx0,0),WW-1);
        int c1 = tid + 512;
        int iy1 = c1 / SXL, ix1 = c1 - iy1 * SXL;
        int gy1 = oy + iy1, gx1 = ox + ix1;
        bool vy1 = (gy1 >= 0) && (gy1 < HH) && (gx1 >= 0) && (gx1 < WW);
        int yx1 = min(max(gy1,0),HH-1) * WW + min(max(gx1,0),WW-1);
        bool has2 = (c1 < SLICE);
#pragma unroll
        for (int iz = 0; iz < SZ; ++iz) {
            int gz = oz + iz;
            bool vz = (gz >= 0) && (gz < DD);
            int gb = min(max(gz,0),DD-1) * (HH*WW);
            f32x2 v0 = img2[gb + yx0];
            if (!(vz && vy0)) { v0.x = 0.0f; v0.y = 0.0f; }
            S[iz*SLICE + c0] = v0;
            if (has2) {
                f32x2 v1 = img2[gb + yx1];
                if (!(vz && vy1)) { v1.x = 0.0f; v1.y = 0.0f; }
                S[iz*SLICE + c1] = v1;
            }
        }
    }
    __syncthreads();

    const int obase = (zb*HH + y)*WW + x;
    const int lzb = zb - oz;        // 2 or 3
    const int lyc = y - oy;         // 5..20
    const int lxc = x - ox;         // 5..20

    // ---- phase-0 copy from LDS ----
#pragma unroll
    for (int k = 0; k < 2; ++k)
        out2[obase + k*(2*HH*WW)] = S[((lzb + 2*k)*SY + lyc)*SXL + lxc];

    unsigned fm = 0;   // failed-slot bitmask, bit = hb*2+s

    // ---- 4 half-batches: (k, phase-pair); 2 slots each ----
#pragma unroll
    for (int hb = 0; hb < 4; ++hb) {
        const int k = hb >> 1;
        const int h = hb & 1;          // phase pair: phases 2h, 2h+1
        const int r = hb & 1;          // ring slot of current

        if (hb < 3) {
            const int kn = (hb + 1) >> 1;
            const int rn = (hb + 1) & 1;
            const int cb = ((hb + 1) & 1) * 6;   // channel base
            unsigned vo = voff0 + (unsigned)(kn * 131072);
            MVF_PAIR(Ra[rn][0], Rb[rn][0], vo, mvf + (cb+0)*MPLANE);
            MVF_PAIR(Ra[rn][1], Rb[rn][1], vo, mvf + (cb+1)*MPLANE);
            MVF_PAIR(Ra[rn][2], Rb[rn][2], vo, mvf + (cb+2)*MPLANE);
            MVF_PAIR(Ra[rn][3], Rb[rn][3], vo, mvf + (cb+3)*MPLANE);
            MVF_PAIR(Ra[rn][4], Rb[rn][4], vo, mvf + (cb+4)*MPLANE);
            // youngers of hb's 12 loads >= these 12 (stores only add) -> safe
            MVF_PAIR(Ra[rn][5], Rb[rn][5], vo, mvf + (cb+5)*MPLANE);
            asm volatile("s_waitcnt vmcnt(12)" ::: "memory");
        } else {
            asm volatile("s_waitcnt vmcnt(0)" ::: "memory");
        }
        __builtin_amdgcn_sched_barrier(0);

        // interp both slots (phases pA = 2h, pB = 2h+1)
        float mvzA = w00*Ra[r][0].x + w01*Ra[r][0].y + w10*Rb[r][0].x + w11*Rb[r][0].y;
        float mvyA = w00*Ra[r][1].x + w01*Ra[r][1].y + w10*Rb[r][1].x + w11*Rb[r][1].y;
        float mvxA = w00*Ra[r][2].x + w01*Ra[r][2].y + w10*Rb[r][2].x + w11*Rb[r][2].y;
        float mvzB = w00*Ra[r][3].x + w01*Ra[r][3].y + w10*Rb[r][3].x + w11*Rb[r][3].y;
        float mvyB = w00*Ra[r][4].x + w01*Ra[r][4].y + w10*Rb[r][4].x + w11*Rb[r][4].y;
        float mvxB = w00*Ra[r][5].x + w01*Ra[r][5].y + w10*Rb[r][5].x + w11*Rb[r][5].y;

        float tzA = (float)(lzb + 2*k) + mvzA;
        float tyA = (float)lyc + 2.0f*mvyA;
        float txA = (float)lxc + 2.0f*mvxA;
        float fzA = floorf(tzA), fyA = floorf(tyA), fxA = floorf(txA);
        int lzA = (int)fzA, lyA = (int)fyA, lxA = (int)fxA;
        float wzA = tzA - fzA, wyA = tyA - fyA, wxA = txA - fxA;
        bool okA = ((unsigned)lzA <= SZ-2) && ((unsigned)lyA <= SY-2) &&
                   ((unsigned)lxA <= SXL-2);
        unsigned baseA = okA ? (unsigned)(((lzA*SY + lyA)*SXL + lxA)*8) : 0u;

        float tzB = (float)(lzb + 2*k) + mvzB;
        float tyB = (float)lyc + 2.0f*mvyB;
        float txB = (float)lxc + 2.0f*mvxB;
        float fzB = floorf(tzB), fyB = floorf(tyB), fxB = floorf(txB);
        int lzB = (int)fzB, lyB = (int)fyB, lxB = (int)fxB;
        float wzB = tzB - fzB, wyB = tyB - fyB, wxB = txB - fxB;
        bool okB = ((unsigned)lzB <= SZ-2) && ((unsigned)lyB <= SY-2) &&
                   ((unsigned)lxB <= SXL-2);
        unsigned baseB = okB ? (unsigned)(((lzB*SY + lyB)*SXL + lxB)*8) : 0u;

        fm |= (okA ? 0u : 1u) << (hb*2 + 0);
        fm |= (okB ? 0u : 1u) << (hb*2 + 1);

        // 16 pinned ds_read_b64: 8 corners (x-pair per read carries both via
        // +8) at immediate offsets within the halo box
        f32x2 qa[8], qb[8];
        DSR(qa[0], baseA, "0");    DSR(qa[1], baseA, "8");
        DSR(qa[2], baseA, "216");  DSR(qa[3], baseA, "224");
        DSR(qa[4], baseA, "5832"); DSR(qa[5], baseA, "5840");
        DSR(qa[6], baseA, "6048"); DSR(qa[7], baseA, "6056");
        DSR(qb[0], baseB, "0");    DSR(qb[1], baseB, "8");
        DSR(qb[2], baseB, "216");  DSR(qb[3], baseB, "224");
        DSR(qb[4], baseB, "5832"); DSR(qb[5], baseB, "5840");
        DSR(qb[6], baseB, "6048"); DSR(qb[7], baseB, "6056");

        asm volatile("s_waitcnt lgkmcnt(8)" ::: "memory");
        __builtin_amdgcn_sched_barrier(0);
        {   // combine + store slot A (phase 2h) — pure trilerp, no masks
            float e0x = qa[0].x + wxA*(qa[1].x - qa[0].x);
            float e0y = qa[0].y + wxA*(qa[1].y - qa[0].y);
            float e1x = qa[2].x + wxA*(qa[3].x - qa[2].x);
            float e1y = qa[2].y + wxA*(qa[3].y - qa[2].y);
            float e2x = qa[4].x + wxA*(qa[5].x - qa[4].x);
            float e2y = qa[4].y + wxA*(qa[5].y - qa[4].y);
            float e3x = qa[6].x + wxA*(qa[7].x - qa[6].x);
            float e3y = qa[6].y + wxA*(qa[7].y - qa[6].y);
            float g0x = e0x + wyA*(e1x - e0x);
            float g0y = e0y + wyA*(e1y - e0y);
            float g1x = e2x + wyA*(e3x - e2x);
            float g1y = e2y + wyA*(e3y - e2y);
            f32x2 res;
            res.x = g0x + wzA*(g1x - g0x);
            res.y = g0y + wzA*(g1y - g0y);
            if (okA) out2[(2*h + 1)*PLANE + k*(2*HH*WW) + obase] = res;
        }
        asm volatile("s_waitcnt lgkmcnt(0)" ::: "memory");
        __builtin_amdgcn_sched_barrier(0);
        {   // combine + store slot B (phase 2h+1)
            float e0x = qb[0].x + wxB*(qb[1].x - qb[0].x);
            float e0y = qb[0].y + wxB*(qb[1].y - qb[0].y);
            float e1x = qb[2].x + wxB*(qb[3].x - qb[2].x);
            float e1y = qb[2].y + wxB*(qb[3].y - qb[2].y);
            float e2x = qb[4].x + wxB*(qb[5].x - qb[4].x);
            float e2y = qb[4].y + wxB*(qb[5].y - qb[4].y);
            float e3x = qb[6].x + wxB*(qb[7].x - qb[6].x);
            float e3y = qb[6].y + wxB*(qb[7].y - qb[6].y);
            float g0x = e0x + wyB*(e1x - e0x);
            float g0y = e0y + wyB*(e1y - e0y);
            float g1x = e2x + wyB*(e3x - e2x);
            float g1y = e2y + wyB*(e3y - e2y);
            f32x2 res;
            res.x = g0x + wzB*(g1x - g0x);
            res.y = g0y + wzB*(g1y - g0y);
            if (okB) out2[(2*h + 2)*PLANE + k*(2*HH*WW) + obase] = res;
        }
    }

    // ---- drain: rare out-of-halo slots, exact clamp+mask global sampler ----
    asm volatile("s_waitcnt vmcnt(0) lgkmcnt(0)" ::: "memory");
#pragma unroll 1
    for (int s = 0; s < 8; ++s) {
        if (fm & (1u << s)) {
            int k = s >> 2, p = s & 3;
            int z = zb + 2*k;
            const float* mp = mvf + (z*(HM*WM) + my0*WM + mx0);
            float mv[3];
#pragma unroll
            for (int ch = 0; ch < 3; ++ch) {
                const float* m = mp + (p*3 + ch)*MPLANE;
                float2 a = *(const float2*)m;
                float2 b = *(const float2*)(m + WM);
                mv[ch] = w00*a.x + w01*a.y + w10*b.x + w11*b.y;
            }
            float zc = (float)z + mv[0];
            float yc = (float)y + 2.0f*mv[1];
            float xc = (float)x + 2.0f*mv[2];
            float zf = floorf(zc), yf = floorf(yc), xf = floorf(xc);
            int zi = (int)zf, yi = (int)yf, xi = (int)xf;
            float wz = zc - zf, wy2 = yc - yf, wx2 = xc - xf;
            int zc0 = min(max(zi,0),DD-1), zc1 = min(max(zi+1,0),DD-1);
            int yc0 = min(max(yi,0),HH-1), yc1 = min(max(yi+1,0),HH-1);
            int xb  = min(max(xi,0),WW-2);
            float s0 = (zi >= 0  && zi < DD)     ? (1.0f - wz)  : 0.0f;
            float s1 = (zi >= -1 && zi < DD - 1) ? wz           : 0.0f;
            float t0 = (yi >= 0  && yi < HH)     ? (1.0f - wy2) : 0.0f;
            float t1 = (yi >= -1 && yi < HH - 1) ? wy2          : 0.0f;
            int d = xi - xb;
            float u0 = (d == 0) ? (1.0f - wx2) : ((d == -1) ? wx2 : 0.0f);
            float u1 = (d == 0) ? wx2 : ((d == 1) ? (1.0f - wx2) : 0.0f);
            int g00 = (zc0*HH + yc0)*WW + xb;
            int g01 = (zc0*HH + yc1)*WW + xb;
            int g10 = (zc1*HH + yc0)*WW + xb;
            int g11 = (zc1*HH + yc1)*WW + xb;
            f32x2 p00L = img2[g00], p00H = img2[g00 + 1];
            f32x2 p01L = img2[g01], p01H = img2[g01 + 1];
            f32x2 p10L = img2[g10], p10H = img2[g10 + 1];
            f32x2 p11L = img2[g11], p11H = img2[g11 + 1];
            float r0a = u0*p00L.x + u1*p00H.x, r0b = u0*p00L.y + u1*p00H.y;
            float r1a = u0*p01L.x + u1*p01H.x, r1b = u0*p01L.y + u1*p01H.y;
            float r2a = u0*p10L.x + u1*p10H.x, r2b = u0*p10L.y + u1*p10H.y;
            float r3a = u0*p11L.x + u1*p11H.x, r3b = u0*p11L.y + u1*p11H.y;
            f32x2 res;
            res.x = s0*(t0*r0a + t1*r1a) + s1*(t0*r2a + t1*r3a);
            res.y = s0*(t0*r0b + t1*r1b) + s1*(t0*r2b + t1*r3b);
            out2[(p + 1)*PLANE + (z*HH + y)*WW + x] = res;
        }
    }
}

extern "C" void kernel_launch(void* const* d_in, const int* in_sizes, int n_in,
                              void* d_out, int out_size, void* d_ws, size_t ws_size,
                              hipStream_t stream) {
    const float* img = (const float*)d_in[0];   // [1,1,48,256,256,2]
    const float* mvf = (const float*)d_in[1];   // [1,4,3,48,128,128]
    float* out = (float*)d_out;                 // [1,5,48,256,256,2]

    // 12 tz * 16 ty * 16 tx = 3072 blocks of 512 threads
    mvf_warp<<<3072, 512, SCELLS * sizeof(f32x2), stream>>>(img, mvf, out);
}

// Round 10
// 59.034 us; speedup vs baseline: 1.3177x; 1.3177x over previous
//
#include <hip/hip_runtime.h>

#define DD 48
#define HH 256
#define WW 256
#define HM 128
#define WM 128
#define PLANE (DD*HH*WW)
#define MPLANE (DD*HM*WM)

// LDS halo: output tile 8z x 16y x 16x, halo +-2z, +-5y, +-5x (zero-padded)
#define SZ 13
#define SY 27
#define SXL 27
#define SLICE (SY*SXL)      // 729
#define SCELLS (SZ*SLICE)   // 9477 cells * 8B = 75816 B -> 2 blocks/CU

typedef __attribute__((ext_vector_type(2))) float f32x2;

// pinned mvf row-pair load: rows my0 and my0+1 (+512B)
#define MVF_PAIR(da, db, vo, bp) \
  asm volatile("global_load_dwordx2 %0, %2, %3\n\t" \
               "global_load_dwordx2 %1, %2, %3 offset:512" \
               : "=&v"(da), "=&v"(db) : "v"(vo), "s"(bp))

// pinned staging load, full 64-bit address
#define GLD(d, p) \
  asm volatile("global_load_dwordx2 %0, %1, off" : "=&v"(d) : "v"(p))

// pinned LDS read with immediate offset (S at LDS offset 0: lone extern shared)
#define DSR(d, a, offstr) \
  asm volatile("ds_read_b64 %0, %1 offset:" offstr : "=v"(d) : "v"(a))

__global__ __launch_bounds__(512, 4) void mvf_warp(
    const float* __restrict__ img,   // [48,256,256,2]
    const float* __restrict__ mvf,   // [4,3,48,128,128]
    float* __restrict__ out)         // [5,48,256,256,2]
{
    extern __shared__ f32x2 S[];     // SCELLS
    const f32x2* img2 = (const f32x2*)img;
    f32x2* out2 = (f32x2*)out;
    const int tid = threadIdx.x;

    // 1536 blocks; XCD k owns y-band ty in {2k, 2k+1}
    const int bid = blockIdx.x;
    const int xcd = bid & 7;
    const int lin = bid >> 3;          // 0..191
    const int tx  = lin & 15;
    const int rest = lin >> 4;         // 0..11
    const int ty  = xcd * 2 + (rest & 1);
    const int tz  = rest >> 1;         // 0..5

    const int z0t = tz * 8, y0t = ty * 16, x0t = tx * 16;
    const int oz = z0t - 2, oy = y0t - 5, ox = x0t - 5;

    const int x  = x0t + (tid & 15);
    const int y  = y0t + ((tid >> 4) & 15);
    const int zb = z0t + (tid >> 8);   // z = zb + 2k, k=0..3

    // ---- mvf bilinear setup (2x half-pixel upsample, clamped) ----
    float ys = fminf(fmaxf((float)y * 0.5f - 0.25f, 0.0f), 127.0f);
    float xs = fminf(fmaxf((float)x * 0.5f - 0.25f, 0.0f), 127.0f);
    int my0 = min((int)ys, HM - 2);
    int mx0 = min((int)xs, WM - 2);
    float wyk = ys - (float)my0, wxk = xs - (float)mx0;
    float w00 = (1.0f - wyk) * (1.0f - wxk);
    float w01 = (1.0f - wyk) * wxk;
    float w10 = wyk * (1.0f - wxk);
    float w11 = wyk * wxk;

    const unsigned voff0 = (unsigned)((zb * (HM*WM) + my0 * WM + mx0) * 4);

    // ring of 2 half-batches (2 phases x 3 ch each): 24 f32x2
    f32x2 Ra[2][6], Rb[2][6];

    // ---- prologue: issue hb0 (k=0, phases 0,1) ----
    MVF_PAIR(Ra[0][0], Rb[0][0], voff0, mvf + 0*MPLANE);
    MVF_PAIR(Ra[0][1], Rb[0][1], voff0, mvf + 1*MPLANE);
    MVF_PAIR(Ra[0][2], Rb[0][2], voff0, mvf + 2*MPLANE);
    MVF_PAIR(Ra[0][3], Rb[0][3], voff0, mvf + 3*MPLANE);
    MVF_PAIR(Ra[0][4], Rb[0][4], voff0, mvf + 4*MPLANE);
    MVF_PAIR(Ra[0][5], Rb[0][5], voff0, mvf + 5*MPLANE);
    __builtin_amdgcn_sched_barrier(0);

    // ---- stage ZERO-PADDED image halo into LDS (batched: one latency hit) ----
    {
        int c0 = tid;
        int iy0 = c0 / SXL, ix0 = c0 - iy0 * SXL;
        int gy0 = oy + iy0, gx0 = ox + ix0;
        bool vy0 = (gy0 >= 0) && (gy0 < HH) && (gx0 >= 0) && (gx0 < WW);
        int yx0 = min(max(gy0,0),HH-1) * WW + min(max(gx0,0),WW-1);
        int c1 = tid + 512;
        int iy1 = c1 / SXL, ix1 = c1 - iy1 * SXL;
        int gy1 = oy + iy1, gx1 = ox + ix1;
        bool vy1 = (gy1 >= 0) && (gy1 < HH) && (gx1 >= 0) && (gx1 < WW);
        int yx1 = min(max(gy1,0),HH-1) * WW + min(max(gx1,0),WW-1);
        bool has2 = (c1 < SLICE);

        f32x2 ga[SZ], gbv[SZ];
#pragma unroll
        for (int iz = 0; iz < SZ; ++iz) {
            int gz = oz + iz;
            int gb = min(max(gz,0),DD-1) * (HH*WW);
            GLD(ga[iz], img2 + gb + yx0);
        }
        if (has2) {
#pragma unroll
            for (int iz = 0; iz < SZ; ++iz) {
                int gz = oz + iz;
                int gb = min(max(gz,0),DD-1) * (HH*WW);
                GLD(gbv[iz], img2 + gb + yx1);
            }
        }
        __builtin_amdgcn_sched_barrier(0);
        asm volatile("s_waitcnt vmcnt(0)" ::: "memory");
        __builtin_amdgcn_sched_barrier(0);
#pragma unroll
        for (int iz = 0; iz < SZ; ++iz) {
            int gz = oz + iz;
            bool vz = (gz >= 0) && (gz < DD);
            f32x2 v0 = ga[iz];
            if (!(vz && vy0)) { v0.x = 0.0f; v0.y = 0.0f; }
            S[iz*SLICE + c0] = v0;
        }
        if (has2) {
#pragma unroll
            for (int iz = 0; iz < SZ; ++iz) {
                int gz = oz + iz;
                bool vz = (gz >= 0) && (gz < DD);
                f32x2 v1 = gbv[iz];
                if (!(vz && vy1)) { v1.x = 0.0f; v1.y = 0.0f; }
                S[iz*SLICE + c1] = v1;
            }
        }
    }
    __syncthreads();

    const int obase = (zb*HH + y)*WW + x;
    const int lzb = zb - oz;        // 2 or 3
    const int lyc = y - oy;         // 5..20
    const int lxc = x - ox;         // 5..20

    // ---- phase-0 copy from LDS ----
#pragma unroll
    for (int k = 0; k < 4; ++k)
        out2[obase + k*(2*HH*WW)] = S[((lzb + 2*k)*SY + lyc)*SXL + lxc];

    unsigned fm = 0;   // failed-slot bitmask, bit = hb*2+s

    // ---- 8 half-batches: (k, phase-pair); 2 slots each ----
#pragma unroll
    for (int hb = 0; hb < 8; ++hb) {
        const int k = hb >> 1;
        const int h = hb & 1;          // phase pair: phases 2h, 2h+1
        const int r = hb & 1;          // ring slot of current

        if (hb < 7) {
            const int kn = (hb + 1) >> 1;
            const int rn = (hb + 1) & 1;
            const int cb = ((hb + 1) & 1) * 6;   // channel base
            unsigned vo = voff0 + (unsigned)(kn * 131072);
            MVF_PAIR(Ra[rn][0], Rb[rn][0], vo, mvf + (cb+0)*MPLANE);
            MVF_PAIR(Ra[rn][1], Rb[rn][1], vo, mvf + (cb+1)*MPLANE);
            MVF_PAIR(Ra[rn][2], Rb[rn][2], vo, mvf + (cb+2)*MPLANE);
            MVF_PAIR(Ra[rn][3], Rb[rn][3], vo, mvf + (cb+3)*MPLANE);
            MVF_PAIR(Ra[rn][4], Rb[rn][4], vo, mvf + (cb+4)*MPLANE);
            // youngers of hb's 12 loads >= these 12 -> vmcnt(12) retires hb's
            MVF_PAIR(Ra[rn][5], Rb[rn][5], vo, mvf + (cb+5)*MPLANE);
            asm volatile("s_waitcnt vmcnt(12)" ::: "memory");
        } else {
            asm volatile("s_waitcnt vmcnt(0)" ::: "memory");
        }
        __builtin_amdgcn_sched_barrier(0);

        // interp both slots (phases pA = 2h, pB = 2h+1)
        float mvzA = w00*Ra[r][0].x + w01*Ra[r][0].y + w10*Rb[r][0].x + w11*Rb[r][0].y;
        float mvyA = w00*Ra[r][1].x + w01*Ra[r][1].y + w10*Rb[r][1].x + w11*Rb[r][1].y;
        float mvxA = w00*Ra[r][2].x + w01*Ra[r][2].y + w10*Rb[r][2].x + w11*Rb[r][2].y;
        float mvzB = w00*Ra[r][3].x + w01*Ra[r][3].y + w10*Rb[r][3].x + w11*Rb[r][3].y;
        float mvyB = w00*Ra[r][4].x + w01*Ra[r][4].y + w10*Rb[r][4].x + w11*Rb[r][4].y;
        float mvxB = w00*Ra[r][5].x + w01*Ra[r][5].y + w10*Rb[r][5].x + w11*Rb[r][5].y;

        float tzA = (float)(lzb + 2*k) + mvzA;
        float tyA = (float)lyc + 2.0f*mvyA;
        float txA = (float)lxc + 2.0f*mvxA;
        float fzA = floorf(tzA), fyA = floorf(tyA), fxA = floorf(txA);
        int lzA = (int)fzA, lyA = (int)fyA, lxA = (int)fxA;
        float wzA = tzA - fzA, wyA = tyA - fyA, wxA = txA - fxA;
        bool okA = ((unsigned)lzA <= SZ-2) && ((unsigned)lyA <= SY-2) &&
                   ((unsigned)lxA <= SXL-2);
        unsigned baseA = okA ? (unsigned)(((lzA*SY + lyA)*SXL + lxA)*8) : 0u;

        float tzB = (float)(lzb + 2*k) + mvzB;
        float tyB = (float)lyc + 2.0f*mvyB;
        float txB = (float)lxc + 2.0f*mvxB;
        float fzB = floorf(tzB), fyB = floorf(tyB), fxB = floorf(txB);
        int lzB = (int)fzB, lyB = (int)fyB, lxB = (int)fxB;
        float wzB = tzB - fzB, wyB = tyB - fyB, wxB = txB - fxB;
        bool okB = ((unsigned)lzB <= SZ-2) && ((unsigned)lyB <= SY-2) &&
                   ((unsigned)lxB <= SXL-2);
        unsigned baseB = okB ? (unsigned)(((lzB*SY + lyB)*SXL + lxB)*8) : 0u;

        fm |= (okA ? 0u : 1u) << (hb*2 + 0);
        fm |= (okB ? 0u : 1u) << (hb*2 + 1);

        // 16 pinned ds_read_b64: 8 corners each (x-pair per read), imm offsets
        f32x2 qa[8], qb[8];
        DSR(qa[0], baseA, "0");    DSR(qa[1], baseA, "8");
        DSR(qa[2], baseA, "216");  DSR(qa[3], baseA, "224");
        DSR(qa[4], baseA, "5832"); DSR(qa[5], baseA, "5840");
        DSR(qa[6], baseA, "6048"); DSR(qa[7], baseA, "6056");
        DSR(qb[0], baseB, "0");    DSR(qb[1], baseB, "8");
        DSR(qb[2], baseB, "216");  DSR(qb[3], baseB, "224");
        DSR(qb[4], baseB, "5832"); DSR(qb[5], baseB, "5840");
        DSR(qb[6], baseB, "6048"); DSR(qb[7], baseB, "6056");

        // single LDS-latency exposure per half-batch
        asm volatile("s_waitcnt lgkmcnt(0)" ::: "memory");
        __builtin_amdgcn_sched_barrier(0);
        {   // combine + store slot A (phase 2h) — pure trilerp, no masks
            float e0x = qa[0].x + wxA*(qa[1].x - qa[0].x);
            float e0y = qa[0].y + wxA*(qa[1].y - qa[0].y);
            float e1x = qa[2].x + wxA*(qa[3].x - qa[2].x);
            float e1y = qa[2].y + wxA*(qa[3].y - qa[2].y);
            float e2x = qa[4].x + wxA*(qa[5].x - qa[4].x);
            float e2y = qa[4].y + wxA*(qa[5].y - qa[4].y);
            float e3x = qa[6].x + wxA*(qa[7].x - qa[6].x);
            float e3y = qa[6].y + wxA*(qa[7].y - qa[6].y);
            float g0x = e0x + wyA*(e1x - e0x);
            float g0y = e0y + wyA*(e1y - e0y);
            float g1x = e2x + wyA*(e3x - e2x);
            float g1y = e2y + wyA*(e3y - e2y);
            f32x2 res;
            res.x = g0x + wzA*(g1x - g0x);
            res.y = g0y + wzA*(g1y - g0y);
            if (okA) out2[(2*h + 1)*PLANE + k*(2*HH*WW) + obase] = res;
        }
        {   // combine + store slot B (phase 2h+1)
            float e0x = qb[0].x + wxB*(qb[1].x - qb[0].x);
            float e0y = qb[0].y + wxB*(qb[1].y - qb[0].y);
            float e1x = qb[2].x + wxB*(qb[3].x - qb[2].x);
            float e1y = qb[2].y + wxB*(qb[3].y - qb[2].y);
            float e2x = qb[4].x + wxB*(qb[5].x - qb[4].x);
            float e2y = qb[4].y + wxB*(qb[5].y - qb[4].y);
            float e3x = qb[6].x + wxB*(qb[7].x - qb[6].x);
            float e3y = qb[6].y + wxB*(qb[7].y - qb[6].y);
            float g0x = e0x + wyB*(e1x - e0x);
            float g0y = e0y + wyB*(e1y - e0y);
            float g1x = e2x + wyB*(e3x - e2x);
            float g1y = e2y + wyB*(e3y - e2y);
            f32x2 res;
            res.x = g0x + wzB*(g1x - g0x);
            res.y = g0y + wzB*(g1y - g0y);
            if (okB) out2[(2*h + 2)*PLANE + k*(2*HH*WW) + obase] = res;
        }
    }

    // ---- drain: rare out-of-halo slots, exact clamp+mask global sampler ----
    asm volatile("s_waitcnt vmcnt(0) lgkmcnt(0)" ::: "memory");
#pragma unroll 1
    for (int s = 0; s < 16; ++s) {
        if (fm & (1u << s)) {
            int k = s >> 2, p = s & 3;
            int z = zb + 2*k;
            const float* mp = mvf + (z*(HM*WM) + my0*WM + mx0);
            float mv[3];
#pragma unroll
            for (int ch = 0; ch < 3; ++ch) {
                const float* m = mp + (p*3 + ch)*MPLANE;
                float2 a = *(const float2*)m;
                float2 b = *(const float2*)(m + WM);
                mv[ch] = w00*a.x + w01*a.y + w10*b.x + w11*b.y;
            }
            float zc = (float)z + mv[0];
            float yc = (float)y + 2.0f*mv[1];
            float xc = (float)x + 2.0f*mv[2];
            float zf = floorf(zc), yf = floorf(yc), xf = floorf(xc);
            int zi = (int)zf, yi = (int)yf, xi = (int)xf;
            float wz = zc - zf, wy2 = yc - yf, wx2 = xc - xf;
            int zc0 = min(max(zi,0),DD-1), zc1 = min(max(zi+1,0),DD-1);
            int yc0 = min(max(yi,0),HH-1), yc1 = min(max(yi+1,0),HH-1);
            int xb  = min(max(xi,0),WW-2);
            float s0 = (zi >= 0  && zi < DD)     ? (1.0f - wz)  : 0.0f;
            float s1 = (zi >= -1 && zi < DD - 1) ? wz           : 0.0f;
            float t0 = (yi >= 0  && yi < HH)     ? (1.0f - wy2) : 0.0f;
            float t1 = (yi >= -1 && yi < HH - 1) ? wy2          : 0.0f;
            int d = xi - xb;
            float u0 = (d == 0) ? (1.0f - wx2) : ((d == -1) ? wx2 : 0.0f);
            float u1 = (d == 0) ? wx2 : ((d == 1) ? (1.0f - wx2) : 0.0f);
            int g00 = (zc0*HH + yc0)*WW + xb;
            int g01 = (zc0*HH + yc1)*WW + xb;
            int g10 = (zc1*HH + yc0)*WW + xb;
            int g11 = (zc1*HH + yc1)*WW + xb;
            f32x2 p00L = img2[g00], p00H = img2[g00 + 1];
            f32x2 p01L = img2[g01], p01H = img2[g01 + 1];
            f32x2 p10L = img2[g10], p10H = img2[g10 + 1];
            f32x2 p11L = img2[g11], p11H = img2[g11 + 1];
            float r0a = u0*p00L.x + u1*p00H.x, r0b = u0*p00L.y + u1*p00H.y;
            float r1a = u0*p01L.x + u1*p01H.x, r1b = u0*p01L.y + u1*p01H.y;
            float r2a = u0*p10L.x + u1*p10H.x, r2b = u0*p10L.y + u1*p10H.y;
            float r3a = u0*p11L.x + u1*p11H.x, r3b = u0*p11L.y + u1*p11H.y;
            f32x2 res;
            res.x = s0*(t0*r0a + t1*r1a) + s1*(t0*r2a + t1*r3a);
            res.y = s0*(t0*r0b + t1*r1b) + s1*(t0*r2b + t1*r3b);
            out2[(p + 1)*PLANE + (z*HH + y)*WW + x] = res;
        }
    }
}

extern "C" void kernel_launch(void* const* d_in, const int* in_sizes, int n_in,
                              void* d_out, int out_size, void* d_ws, size_t ws_size,
                              hipStream_t stream) {
    const float* img = (const float*)d_in[0];   // [1,1,48,256,256,2]
    const float* mvf = (const float*)d_in[1];   // [1,4,3,48,128,128]
    float* out = (float*)d_out;                 // [1,5,48,256,256,2]

    // 6 tz * 16 ty * 16 tx = 1536 blocks of 512 threads
    mvf_warp<<<1536, 512, SCELLS * sizeof(f32x2), stream>>>(img, mvf, out);
}

// Round 11
// 57.968 us; speedup vs baseline: 1.3420x; 1.0184x over previous
//
#include <hip/hip_runtime.h>

#define DD 48
#define HH 256
#define WW 256
#define HM 128
#define WM 128
#define PLANE (DD*HH*WW)
#define MPLANE (DD*HM*WM)

// LDS halo: output tile 8z x 16y x 16x, halo +-2z, +-5y, +-5x (zero-padded)
#define SZ 13
#define SY 27
#define SXL 27
#define SLICE (SY*SXL)      // 729
#define SCELLS (SZ*SLICE)   // 9477 cells * 8B = 75816 B -> 2 blocks/CU

typedef __attribute__((ext_vector_type(2))) float f32x2;
typedef __attribute__((ext_vector_type(4))) float f32x4;

// pinned mvf row-pair load: rows my0 and my0+1 (+512B)
#define MVF_PAIR(da, db, vo, bp) \
  asm volatile("global_load_dwordx2 %0, %2, %3\n\t" \
               "global_load_dwordx2 %1, %2, %3 offset:512" \
               : "=&v"(da), "=&v"(db) : "v"(vo), "s"(bp))

// pinned staging load, full 64-bit address
#define GLD(d, p) \
  asm volatile("global_load_dwordx2 %0, %1, off" : "=&v"(d) : "v"(p))

// pinned paired LDS read: two b64 at base + 8*o0 / base + 8*o1
#define DSR2(d, a, o0, o1) \
  asm volatile("ds_read2_b64 %0, %1 offset0:" o0 " offset1:" o1 \
               : "=v"(d) : "v"(a))

__global__ __launch_bounds__(512, 4) void mvf_warp(
    const float* __restrict__ img,   // [48,256,256,2]
    const float* __restrict__ mvf,   // [4,3,48,128,128]
    float* __restrict__ out)         // [5,48,256,256,2]
{
    extern __shared__ f32x2 S[];     // SCELLS
    const f32x2* img2 = (const f32x2*)img;
    f32x2* out2 = (f32x2*)out;
    const int tid = threadIdx.x;

    // 1536 blocks; XCD k owns y-band ty in {2k, 2k+1}
    const int bid = blockIdx.x;
    const int xcd = bid & 7;
    const int lin = bid >> 3;          // 0..191
    const int tx  = lin & 15;
    const int rest = lin >> 4;         // 0..11
    const int ty  = xcd * 2 + (rest & 1);
    const int tz  = rest >> 1;         // 0..5

    const int z0t = tz * 8, y0t = ty * 16, x0t = tx * 16;
    const int oz = z0t - 2, oy = y0t - 5, ox = x0t - 5;

    const int x  = x0t + (tid & 15);
    const int y  = y0t + ((tid >> 4) & 15);
    const int zb = z0t + (tid >> 8);   // z = zb + 2k, k=0..3

    // ---- mvf bilinear setup (2x half-pixel upsample, clamped) ----
    float ys = fminf(fmaxf((float)y * 0.5f - 0.25f, 0.0f), 127.0f);
    float xs = fminf(fmaxf((float)x * 0.5f - 0.25f, 0.0f), 127.0f);
    int my0 = min((int)ys, HM - 2);
    int mx0 = min((int)xs, WM - 2);
    float wyk = ys - (float)my0, wxk = xs - (float)mx0;
    float w00 = (1.0f - wyk) * (1.0f - wxk);
    float w01 = (1.0f - wyk) * wxk;
    float w10 = wyk * (1.0f - wxk);
    float w11 = wyk * wxk;

    const unsigned voff0 = (unsigned)((zb * (HM*WM) + my0 * WM + mx0) * 4);

    // ring of 3 half-batches (each: 2 phases x 3 ch row-pairs): 36 f32x2
    f32x2 Ra[3][6], Rb[3][6];

    // ---- prologue: issue hb0 only (k=0, phases 0,1) — keeps ring liveness
    // low while the 26-reg staging batch is in flight ----
    MVF_PAIR(Ra[0][0], Rb[0][0], voff0, mvf + 0*MPLANE);
    MVF_PAIR(Ra[0][1], Rb[0][1], voff0, mvf + 1*MPLANE);
    MVF_PAIR(Ra[0][2], Rb[0][2], voff0, mvf + 2*MPLANE);
    MVF_PAIR(Ra[0][3], Rb[0][3], voff0, mvf + 3*MPLANE);
    MVF_PAIR(Ra[0][4], Rb[0][4], voff0, mvf + 4*MPLANE);
    MVF_PAIR(Ra[0][5], Rb[0][5], voff0, mvf + 5*MPLANE);
    __builtin_amdgcn_sched_barrier(0);

    // ---- stage ZERO-PADDED image halo into LDS (batched: one latency hit) ----
    {
        int c0 = tid;
        int iy0 = c0 / SXL, ix0 = c0 - iy0 * SXL;
        int gy0 = oy + iy0, gx0 = ox + ix0;
        bool vy0 = (gy0 >= 0) && (gy0 < HH) && (gx0 >= 0) && (gx0 < WW);
        int yx0 = min(max(gy0,0),HH-1) * WW + min(max(gx0,0),WW-1);
        int c1 = tid + 512;
        int iy1 = c1 / SXL, ix1 = c1 - iy1 * SXL;
        int gy1 = oy + iy1, gx1 = ox + ix1;
        bool vy1 = (gy1 >= 0) && (gy1 < HH) && (gx1 >= 0) && (gx1 < WW);
        int yx1 = min(max(gy1,0),HH-1) * WW + min(max(gx1,0),WW-1);
        bool has2 = (c1 < SLICE);

        f32x2 ga[SZ], gbv[SZ];
#pragma unroll
        for (int iz = 0; iz < SZ; ++iz) {
            int gz = oz + iz;
            int gb = min(max(gz,0),DD-1) * (HH*WW);
            GLD(ga[iz], img2 + gb + yx0);
        }
        if (has2) {
#pragma unroll
            for (int iz = 0; iz < SZ; ++iz) {
                int gz = oz + iz;
                int gb = min(max(gz,0),DD-1) * (HH*WW);
                GLD(gbv[iz], img2 + gb + yx1);
            }
        }
        __builtin_amdgcn_sched_barrier(0);
        asm volatile("s_waitcnt vmcnt(0)" ::: "memory");
        __builtin_amdgcn_sched_barrier(0);
#pragma unroll
        for (int iz = 0; iz < SZ; ++iz) {
            int gz = oz + iz;
            bool vz = (gz >= 0) && (gz < DD);
            f32x2 v0 = ga[iz];
            if (!(vz && vy0)) { v0.x = 0.0f; v0.y = 0.0f; }
            S[iz*SLICE + c0] = v0;
        }
        if (has2) {
#pragma unroll
            for (int iz = 0; iz < SZ; ++iz) {
                int gz = oz + iz;
                bool vz = (gz >= 0) && (gz < DD);
                f32x2 v1 = gbv[iz];
                if (!(vz && vy1)) { v1.x = 0.0f; v1.y = 0.0f; }
                S[iz*SLICE + c1] = v1;
            }
        }
    }

    // ---- issue hb1 (k=0, phases 2,3) before the barrier ----
    MVF_PAIR(Ra[1][0], Rb[1][0], voff0, mvf + 6*MPLANE);
    MVF_PAIR(Ra[1][1], Rb[1][1], voff0, mvf + 7*MPLANE);
    MVF_PAIR(Ra[1][2], Rb[1][2], voff0, mvf + 8*MPLANE);
    MVF_PAIR(Ra[1][3], Rb[1][3], voff0, mvf + 9*MPLANE);
    MVF_PAIR(Ra[1][4], Rb[1][4], voff0, mvf + 10*MPLANE);
    MVF_PAIR(Ra[1][5], Rb[1][5], voff0, mvf + 11*MPLANE);
    __builtin_amdgcn_sched_barrier(0);
    __syncthreads();

    const int obase = (zb*HH + y)*WW + x;
    const int lzb = zb - oz;        // 2 or 3
    const int lyc = y - oy;         // 5..20
    const int lxc = x - ox;         // 5..20

    // ---- phase-0 copy from LDS ----
#pragma unroll
    for (int k = 0; k < 4; ++k)
        out2[obase + k*(2*HH*WW)] = S[((lzb + 2*k)*SY + lyc)*SXL + lxc];

    unsigned fm = 0;   // failed-slot bitmask, bit = hb*2+s

    // ---- 8 half-batches: (k, phase-pair); 2 slots each; prefetch depth 2 ----
#pragma unroll
    for (int hb = 0; hb < 8; ++hb) {
        const int k = hb >> 1;
        const int h = hb & 1;          // phase pair: phases 2h, 2h+1
        const int r = hb % 3;          // ring slot of current

        if (hb < 6) {
            const int hbn = hb + 2;
            const int rn = hbn % 3;
            const int cb = (hbn & 1) * 6;        // channel base
            unsigned vo = voff0 + (unsigned)((hbn >> 1) * 131072);
            MVF_PAIR(Ra[rn][0], Rb[rn][0], vo, mvf + (cb+0)*MPLANE);
            MVF_PAIR(Ra[rn][1], Rb[rn][1], vo, mvf + (cb+1)*MPLANE);
            MVF_PAIR(Ra[rn][2], Rb[rn][2], vo, mvf + (cb+2)*MPLANE);
            MVF_PAIR(Ra[rn][3], Rb[rn][3], vo, mvf + (cb+3)*MPLANE);
            MVF_PAIR(Ra[rn][4], Rb[rn][4], vo, mvf + (cb+4)*MPLANE);
            MVF_PAIR(Ra[rn][5], Rb[rn][5], vo, mvf + (cb+5)*MPLANE);
            // >=24 younger loads (hb+1, hb+2) outstanding -> hb's retired
            asm volatile("s_waitcnt vmcnt(24)" ::: "memory");
        } else if (hb == 6) {
            asm volatile("s_waitcnt vmcnt(12)" ::: "memory");
        } else {
            asm volatile("s_waitcnt vmcnt(0)" ::: "memory");
        }
        __builtin_amdgcn_sched_barrier(0);

        // interp both slots (phases pA = 2h, pB = 2h+1)
        float mvzA = w00*Ra[r][0].x + w01*Ra[r][0].y + w10*Rb[r][0].x + w11*Rb[r][0].y;
        float mvyA = w00*Ra[r][1].x + w01*Ra[r][1].y + w10*Rb[r][1].x + w11*Rb[r][1].y;
        float mvxA = w00*Ra[r][2].x + w01*Ra[r][2].y + w10*Rb[r][2].x + w11*Rb[r][2].y;
        float mvzB = w00*Ra[r][3].x + w01*Ra[r][3].y + w10*Rb[r][3].x + w11*Rb[r][3].y;
        float mvyB = w00*Ra[r][4].x + w01*Ra[r][4].y + w10*Rb[r][4].x + w11*Rb[r][4].y;
        float mvxB = w00*Ra[r][5].x + w01*Ra[r][5].y + w10*Rb[r][5].x + w11*Rb[r][5].y;

        float tzA = (float)(lzb + 2*k) + mvzA;
        float tyA = (float)lyc + 2.0f*mvyA;
        float txA = (float)lxc + 2.0f*mvxA;
        float fzA = floorf(tzA), fyA = floorf(tyA), fxA = floorf(txA);
        int lzA = (int)fzA, lyA = (int)fyA, lxA = (int)fxA;
        float wzA = tzA - fzA, wyA = tyA - fyA, wxA = txA - fxA;
        bool okA = ((unsigned)lzA <= SZ-2) && ((unsigned)lyA <= SY-2) &&
                   ((unsigned)lxA <= SXL-2);
        unsigned baseA = okA ? (unsigned)(((lzA*SY + lyA)*SXL + lxA)*8) : 0u;

        float tzB = (float)(lzb + 2*k) + mvzB;
        float tyB = (float)lyc + 2.0f*mvyB;
        float txB = (float)lxc + 2.0f*mvxB;
        float fzB = floorf(tzB), fyB = floorf(tyB), fxB = floorf(txB);
        int lzB = (int)fzB, lyB = (int)fyB, lxB = (int)fxB;
        float wzB = tzB - fzB, wyB = tyB - fyB, wxB = txB - fxB;
        bool okB = ((unsigned)lzB <= SZ-2) && ((unsigned)lyB <= SY-2) &&
                   ((unsigned)lxB <= SXL-2);
        unsigned baseB = okB ? (unsigned)(((lzB*SY + lyB)*SXL + lxB)*8) : 0u;

        fm |= (okA ? 0u : 1u) << (hb*2 + 0);
        fm |= (okB ? 0u : 1u) << (hb*2 + 1);

        unsigned baseZA = baseA + 5832u;   // z+1 slice
        unsigned baseZB = baseB + 5832u;

        // 8 paired LDS reads (ds_read2_b64): 4 per slot, offsets in 8B units
        // (0,1) = (y0,x0),(y0,x1); (27,28) = (y1,x0),(y1,x1)
        f32x4 pa01, pa23, pa45, pa67, pb01, pb23, pb45, pb67;
        DSR2(pa01, baseA,  "0",  "1");
        DSR2(pa23, baseA,  "27", "28");
        DSR2(pa45, baseZA, "0",  "1");
        DSR2(pa67, baseZA, "27", "28");
        DSR2(pb01, baseB,  "0",  "1");
        DSR2(pb23, baseB,  "27", "28");
        DSR2(pb45, baseZB, "0",  "1");
        DSR2(pb67, baseZB, "27", "28");

        // single LDS-latency exposure per half-batch
        asm volatile("s_waitcnt lgkmcnt(0)" ::: "memory");
        __builtin_amdgcn_sched_barrier(0);
        {   // combine + store slot A (phase 2h) — pure trilerp, no masks
            float e0x = pa01.x + wxA*(pa01.z - pa01.x);
            float e0y = pa01.y + wxA*(pa01.w - pa01.y);
            float e1x = pa23.x + wxA*(pa23.z - pa23.x);
            float e1y = pa23.y + wxA*(pa23.w - pa23.y);
            float e2x = pa45.x + wxA*(pa45.z - pa45.x);
            float e2y = pa45.y + wxA*(pa45.w - pa45.y);
            float e3x = pa67.x + wxA*(pa67.z - pa67.x);
            float e3y = pa67.y + wxA*(pa67.w - pa67.y);
            float g0x = e0x + wyA*(e1x - e0x);
            float g0y = e0y + wyA*(e1y - e0y);
            float g1x = e2x + wyA*(e3x - e2x);
            float g1y = e2y + wyA*(e3y - e2y);
            f32x2 res;
            res.x = g0x + wzA*(g1x - g0x);
            res.y = g0y + wzA*(g1y - g0y);
            if (okA) out2[(2*h + 1)*PLANE + k*(2*HH*WW) + obase] = res;
        }
        {   // combine + store slot B (phase 2h+1)
            float e0x = pb01.x + wxB*(pb01.z - pb01.x);
            float e0y = pb01.y + wxB*(pb01.w - pb01.y);
            float e1x = pb23.x + wxB*(pb23.z - pb23.x);
            float e1y = pb23.y + wxB*(pb23.w - pb23.y);
            float e2x = pb45.x + wxB*(pb45.z - pb45.x);
            float e2y = pb45.y + wxB*(pb45.w - pb45.y);
            float e3x = pb67.x + wxB*(pb67.z - pb67.x);
            float e3y = pb67.y + wxB*(pb67.w - pb67.y);
            float g0x = e0x + wyB*(e1x - e0x);
            float g0y = e0y + wyB*(e1y - e0y);
            float g1x = e2x + wyB*(e3x - e2x);
            float g1y = e2y + wyB*(e3y - e2y);
            f32x2 res;
            res.x = g0x + wzB*(g1x - g0x);
            res.y = g0y + wzB*(g1y - g0y);
            if (okB) out2[(2*h + 2)*PLANE + k*(2*HH*WW) + obase] = res;
        }
    }

    // ---- drain: rare out-of-halo slots, exact clamp+mask global sampler ----
    asm volatile("s_waitcnt vmcnt(0) lgkmcnt(0)" ::: "memory");
#pragma unroll 1
    for (int s = 0; s < 16; ++s) {
        if (fm & (1u << s)) {
            int k = s >> 2, p = s & 3;
            int z = zb + 2*k;
            const float* mp = mvf + (z*(HM*WM) + my0*WM + mx0);
            float mv[3];
#pragma unroll
            for (int ch = 0; ch < 3; ++ch) {
                const float* m = mp + (p*3 + ch)*MPLANE;
                float2 a = *(const float2*)m;
                float2 b = *(const float2*)(m + WM);
                mv[ch] = w00*a.x + w01*a.y + w10*b.x + w11*b.y;
            }
            float zc = (float)z + mv[0];
            float yc = (float)y + 2.0f*mv[1];
            float xc = (float)x + 2.0f*mv[2];
            float zf = floorf(zc), yf = floorf(yc), xf = floorf(xc);
            int zi = (int)zf, yi = (int)yf, xi = (int)xf;
            float wz = zc - zf, wy2 = yc - yf, wx2 = xc - xf;
            int zc0 = min(max(zi,0),DD-1), zc1 = min(max(zi+1,0),DD-1);
            int yc0 = min(max(yi,0),HH-1), yc1 = min(max(yi+1,0),HH-1);
            int xb  = min(max(xi,0),WW-2);
            float s0 = (zi >= 0  && zi < DD)     ? (1.0f - wz)  : 0.0f;
            float s1 = (zi >= -1 && zi < DD - 1) ? wz           : 0.0f;
            float t0 = (yi >= 0  && yi < HH)     ? (1.0f - wy2) : 0.0f;
            float t1 = (yi >= -1 && yi < HH - 1) ? wy2          : 0.0f;
            int d = xi - xb;
            float u0 = (d == 0) ? (1.0f - wx2) : ((d == -1) ? wx2 : 0.0f);
            float u1 = (d == 0) ? wx2 : ((d == 1) ? (1.0f - wx2) : 0.0f);
            int g00 = (zc0*HH + yc0)*WW + xb;
            int g01 = (zc0*HH + yc1)*WW + xb;
            int g10 = (zc1*HH + yc0)*WW + xb;
            int g11 = (zc1*HH + yc1)*WW + xb;
            f32x2 p00L = img2[g00], p00H = img2[g00 + 1];
            f32x2 p01L = img2[g01], p01H = img2[g01 + 1];
            f32x2 p10L = img2[g10], p10H = img2[g10 + 1];
            f32x2 p11L = img2[g11], p11H = img2[g11 + 1];
            float r0a = u0*p00L.x + u1*p00H.x, r0b = u0*p00L.y + u1*p00H.y;
            float r1a = u0*p01L.x + u1*p01H.x, r1b = u0*p01L.y + u1*p01H.y;
            float r2a = u0*p10L.x + u1*p10H.x, r2b = u0*p10L.y + u1*p10H.y;
            float r3a = u0*p11L.x + u1*p11H.x, r3b = u0*p11L.y + u1*p11H.y;
            f32x2 res;
            res.x = s0*(t0*r0a + t1*r1a) + s1*(t0*r2a + t1*r3a);
            res.y = s0*(t0*r0b + t1*r1b) + s1*(t0*r2b + t1*r3b);
            out2[(p + 1)*PLANE + (z*HH + y)*WW + x] = res;
        }
    }
}

extern "C" void kernel_launch(void* const* d_in, const int* in_sizes, int n_in,
                              void* d_out, int out_size, void* d_ws, size_t ws_size,
                              hipStream_t stream) {
    const float* img = (const float*)d_in[0];   // [1,1,48,256,256,2]
    const float* mvf = (const float*)d_in[1];   // [1,4,3,48,128,128]
    float* out = (float*)d_out;                 // [1,5,48,256,256,2]

    // 6 tz * 16 ty * 16 tx = 1536 blocks of 512 threads
    mvf_warp<<<1536, 512, SCELLS * sizeof(f32x2), stream>>>(img, mvf, out);
}